// Round 1
// baseline (300.247 us; speedup 1.0000x reference)
//
#include <hip/hip_runtime.h>
#include <hip/hip_bf16.h>
#include <stdint.h>

// Problem constants
#define NB 16       // batch
#define NC 128      // C_in == C_out
#define NK 128      // modes
#define NSP 16384   // spatial N
#define SPLIT 32    // split-K chunks per batch for GEMM1
#define CHUNK 512   // NSP / SPLIT
#define BK 64       // reduction tile for GEMM1

typedef float f32x4 __attribute__((ext_vector_type(4)));
typedef __bf16 bf16x8 __attribute__((ext_vector_type(8)));

__device__ __forceinline__ unsigned short f32_to_bf16(float a) {
  unsigned int u = __float_as_uint(a);
  return (unsigned short)((u + 0x7fffu + ((u >> 16) & 1u)) >> 16);
}

__device__ __forceinline__ unsigned int pack_bf16(float a, float b) {
  unsigned int ua = __float_as_uint(a);
  unsigned int ub = __float_as_uint(b);
  ua = (ua + 0x7fffu + ((ua >> 16) & 1u)) >> 16;
  ub = (ub + 0x7fffu + ((ub >> 16) & 1u)) & 0xffff0000u;
  return ua | ub;
}

// async global->LDS copy, 16 B per lane; LDS dst = base + lane*16 (wave-uniform base)
__device__ __forceinline__ void gl_lds16(const void* g, void* l) {
  __builtin_amdgcn_global_load_lds(
      (const __attribute__((address_space(1))) unsigned int*)g,
      (__attribute__((address_space(3))) unsigned int*)l, 16, 0, 0);
}

// ---------------------------------------------------------------------------
// k0: merged prep. Blocks 0..2047: wbases (NSP x NK) f32 -> wbT (NK x NSP) bf16
// (LDS tile transpose). Blocks 2048..4095: bases f32 -> bf16 straight convert.
__global__ void k0_prep(const float* __restrict__ wb, unsigned short* __restrict__ wbT,
                        const float* __restrict__ bases, unsigned short* __restrict__ bb) {
  __shared__ float tile[32][33];
  if (blockIdx.x < 2048) {
    int bid = blockIdx.x;
    int kt = (bid & 3) * 32;
    int nt = (bid >> 2) * 32;
    int tx = threadIdx.x & 31;
    int ty = threadIdx.x >> 5;  // 0..7
#pragma unroll
    for (int i = 0; i < 32; i += 8)
      tile[ty + i][tx] = wb[(size_t)(nt + ty + i) * NK + kt + tx];
    __syncthreads();
#pragma unroll
    for (int i = 0; i < 32; i += 8)
      wbT[(size_t)(kt + ty + i) * NSP + nt + tx] = f32_to_bf16(tile[tx][ty + i]);
  } else {
    int i = (blockIdx.x - 2048) * 256 + threadIdx.x;
    float4 v = ((const float4*)bases)[i];
    uint2 o;
    o.x = pack_bf16(v.x, v.y);
    o.y = pack_bf16(v.z, v.w);
    ((uint2*)bb)[i] = o;
  }
}

// ---------------------------------------------------------------------------
// k1 v3: split-K GEMM1, 2-phase double-buffered pipeline (T3-min + T14).
// Grid 512 = (b, chunk); 512 threads = 8 waves. Output 128c x 128k per block;
// wave tile 64c x 32k (4x2 of 16x16x32).
//   - per iter: issue NEXT tile's wbT gl_lds + x reg-loads FIRST, then compute
//     current LDS buffers, then pack+ds_write the x regs, then ONE barrier.
//     The in-flight loads overlap the MFMA+ds_read phase instead of being
//     drained cold at a barrier immediately after issue.
//   - ldsB (wbT) is XOR-swizzled (slot ^= row&7) via pre-swizzled global source
//     (gl_lds dst must stay linear) -> uniform 8-phase ds_read_b128 (optimal).
//   - ldsA keeps the fragment-ordered layout (conflict-free by construction).
__global__ __launch_bounds__(512, 4)
void k1_proj(const float* __restrict__ x, const unsigned short* __restrict__ wbT,
             float* __restrict__ part) {
  int blk = blockIdx.x;
  int b = blk >> 5;      // / SPLIT
  int chunk = blk & 31;  // % SPLIT
  int n0 = chunk * CHUNK;
  __shared__ unsigned short ldsA[2][8 * 128 * 8];  // 2 x 16 KB fragment-ordered (x)
  __shared__ unsigned short ldsB[2][128 * 64];     // 2 x 16 KB row-major swizzled (wbT)
  int tid = threadIdx.x;
  int lane = tid & 63;
  int wave = tid >> 6;        // 0..7
  int cb = (wave & 1) * 64;   // c quadrant
  int kb = (wave >> 1) * 32;  // k-mode block
  int r = lane & 15;
  int q = lane >> 4;

  f32x4 acc[4][2];
#pragma unroll
  for (int t = 0; t < 4; ++t)
#pragma unroll
    for (int u = 0; u < 2; ++u) acc[t][u] = (f32x4){0.f, 0.f, 0.f, 0.f};

  // x staging: thread -> (g = tid&7 covering n_local g*8..+8, row0 = tid>>3)
  int g = tid & 7;
  int row0 = tid >> 3;  // 0..63, +64 on round 2
  const float* xbase = x + (size_t)(b * NC) * NSP + n0 + g * 8;

  // wbT copy: instr i = wave*2+j covers k-rows 8i..8i+7; lane -> row 8i+(lane>>3).
  // Linear LDS dst slot = lane&7; source column slot = (lane&7)^(row&7)
  // = (lane&7)^(lane>>3)  (8i contributes 0 mod 8).
  const unsigned short* wsrc =
      wbT + n0 + (size_t)(lane >> 3) * NSP + ((lane & 7) ^ (lane >> 3)) * 8;

  // ---- prologue: stage it=0 into buffer 0
#pragma unroll
  for (int j = 0; j < 2; ++j) {
    int i = wave * 2 + j;
    gl_lds16(wsrc + (size_t)(i * 8) * NSP, (char*)ldsB[0] + i * 1024);
  }
  {
    uint4* wA = (uint4*)ldsA[0];
#pragma unroll
    for (int jj = 0; jj < 2; ++jj) {
      int row = row0 + jj * 64;
      const float4* p = (const float4*)(xbase + (size_t)row * NSP);
      float4 a0 = p[0];
      float4 a1 = p[1];
      uint4 u;
      u.x = pack_bf16(a0.x, a0.y);
      u.y = pack_bf16(a0.z, a0.w);
      u.z = pack_bf16(a1.x, a1.y);
      u.w = pack_bf16(a1.z, a1.w);
      wA[g * 128 + row] = u;
    }
  }
  __syncthreads();

  for (int it = 0; it < CHUNK / BK; ++it) {  // 8 iterations
    int cur = it & 1;
    bool pf = (it + 1) < (CHUNK / BK);
    float4 a0[2], a1[2];
    if (pf) {
      // issue next tile's loads BEFORE compute (latency hides under MFMA phase)
#pragma unroll
      for (int j = 0; j < 2; ++j) {
        int i = wave * 2 + j;
        gl_lds16(wsrc + (size_t)(i * 8) * NSP + (it + 1) * BK,
                 (char*)ldsB[cur ^ 1] + i * 1024);
      }
#pragma unroll
      for (int jj = 0; jj < 2; ++jj) {
        int row = row0 + jj * 64;
        const float4* p = (const float4*)(xbase + (size_t)row * NSP + (it + 1) * BK);
        a0[jj] = p[0];
        a1[jj] = p[1];
      }
    }
    // ---- compute current buffers
    const bf16x8* pA = (const bf16x8*)ldsA[cur];
    const char* pB = (const char*)ldsB[cur];
#pragma unroll
    for (int s = 0; s < 2; ++s) {
      bf16x8 af[4], bf[2];
      int s4q = s * 4 + q;
#pragma unroll
      for (int t = 0; t < 4; ++t) af[t] = pA[s4q * 128 + cb + 16 * t + r];
#pragma unroll
      for (int u = 0; u < 2; ++u) {
        int rw = kb + 16 * u + r;
        bf[u] = *(const bf16x8*)(pB + rw * 128 + ((s4q ^ (r & 7)) << 4));
      }
#pragma unroll
      for (int t = 0; t < 4; ++t)
#pragma unroll
        for (int u = 0; u < 2; ++u)
          acc[t][u] = __builtin_amdgcn_mfma_f32_16x16x32_bf16(af[t], bf[u],
                                                              acc[t][u], 0, 0, 0);
    }
    // ---- write back prefetched x into the other A buffer
    if (pf) {
      uint4* wA = (uint4*)ldsA[cur ^ 1];
#pragma unroll
      for (int jj = 0; jj < 2; ++jj) {
        int row = row0 + jj * 64;
        uint4 u;
        u.x = pack_bf16(a0[jj].x, a0[jj].y);
        u.y = pack_bf16(a0[jj].z, a0[jj].w);
        u.z = pack_bf16(a1[jj].x, a1[jj].y);
        u.w = pack_bf16(a1[jj].z, a1[jj].w);
        wA[g * 128 + row] = u;
      }
    }
    __syncthreads();  // one barrier per iter: drains gl_lds + ds_writes
  }

  // C/D layout: col = lane&15, row = (lane>>4)*4 + reg  [m89-verified]
  float* pp = part + (size_t)blk * (NC * NK);
  int rq = q * 4;
#pragma unroll
  for (int t = 0; t < 4; ++t)
#pragma unroll
    for (int u = 0; u < 2; ++u)
#pragma unroll
      for (int v = 0; v < 4; ++v)
        pp[(cb + 16 * t + rq + v) * NK + kb + 16 * u + r] = acc[t][u][v];
}

// ---------------------------------------------------------------------------
// k1b: reduce SPLIT partials -> x_co fp32. float2-vectorized.
__global__ __launch_bounds__(256)
void k1b_reduce(const float* __restrict__ part, float* __restrict__ x_co) {
  int idx = blockIdx.x * 256 + threadIdx.x;  // 131072 float2 sites
  int b = idx >> 13;                         // / (NC*NK/2)
  int r2 = idx & 8191;
  const float2* p = (const float2*)(part + (size_t)b * SPLIT * (NC * NK)) + r2;
  float2 s = {0.f, 0.f};
#pragma unroll
  for (int c = 0; c < SPLIT; ++c) {
    float2 v = p[(size_t)c * (NC * NK / 2)];
    s.x += v.x;
    s.y += v.y;
  }
  ((float2*)x_co)[idx] = s;
}

// ---------------------------------------------------------------------------
// k2 v2: per-mode channel mix, o-PAIR per block. Block = (b, o-pair),
// lanes = k (128). Halves x_co L2 traffic and load-instruction count vs
// one-o-per-block; same-o blocks stay 64 apart (64 % 8 == 0 -> same XCD,
// W slices stay L2-local). Fully coalesced (k contiguous in both operands).
__global__ __launch_bounds__(128)
void k2_mix(const float* __restrict__ x_co, const float* __restrict__ W,
            unsigned short* __restrict__ xhat_bf) {
  int b = blockIdx.x >> 6;          // 0..15
  int o0 = (blockIdx.x & 63) * 2;   // 0,2,..,126
  int k = threadIdx.x;
  const float* xc = x_co + (size_t)b * NC * NK + k;
  const float* w0 = W + (size_t)o0 * NK + k;
  float a0 = 0.f, a1 = 0.f;
#pragma unroll 4
  for (int i = 0; i < NC; ++i) {
    float v = xc[(size_t)i * NK];
    a0 += v * w0[(size_t)i * (NC * NK)];
    a1 += v * w0[(size_t)i * (NC * NK) + NK];
  }
  size_t base = ((size_t)b * NC + o0) * NK + k;
  xhat_bf[base] = f32_to_bf16(a0);
  xhat_bf[base + NK] = f32_to_bf16(a1);
}

// ---------------------------------------------------------------------------
// k3 v3: out (2048 x NSP) = xhat (2048 x 128) @ bases^T. Grid 512 =
// 16 mo-tiles x 32 n-chunks of 512. A-fragments in registers; B (128 n-rows x
// 128 k bf16 = 32 KB) double-buffered via async global_load_lds.
// v3: XOR-swizzled B layout (slot ^= row&15) via pre-swizzled global source,
// replacing the pad scheme -> uniform 8-phase ds_read_b128 (was a non-uniform
// 16-phase pattern = 2x the bank minimum).
__global__ __launch_bounds__(256, 2)
void k3_recon(const unsigned short* __restrict__ xhat_bf,
              const unsigned short* __restrict__ bases_bf,
              float* __restrict__ out) {
  int blk = blockIdx.x;
  int mo0 = (blk & 15) * 128;
  int n0 = (blk >> 4) * 512;
  __shared__ unsigned short ldsB[2][128 * 128];  // 2 x 32 KB swizzled row-major
  int tid = threadIdx.x;
  int lane = tid & 63;
  int wave = tid >> 6;  // 0..3
  int mb = (wave & 1) * 64;
  int nb = (wave >> 1) * 64;
  int r = lane & 15;
  int q = lane >> 4;

  // A fragments: rows mo0+mb+16t+r, k = s*32+q*8  (16 x 16 B loads, L2/L3-hot)
  bf16x8 af[4][4];
#pragma unroll
  for (int t = 0; t < 4; ++t)
#pragma unroll
    for (int s = 0; s < 4; ++s)
      af[t][s] = *(const bf16x8*)(xhat_bf +
                                  (size_t)(mo0 + mb + 16 * t + r) * NK +
                                  s * 32 + q * 8);

  // B copy: instr i = wave*8+jj covers n-rows 4i..4i+3; lane -> row 4i+(lane>>4).
  // Linear dst slot = lane&15; source column slot = (lane&15)^(row&15)
  // = (lane&15) ^ (((i&3)<<2) | (lane>>4)).
  int rlane = lane >> 4;
  int slane = lane & 15;

#pragma unroll
  for (int jj = 0; jj < 8; ++jj) {
    int i = wave * 8 + jj;
    int c = slane ^ (((i & 3) << 2) | rlane);
    gl_lds16(bases_bf + (size_t)(n0 + i * 4 + rlane) * NK + c * 8,
             (char*)ldsB[0] + i * 1024);
  }

  for (int sub = 0; sub < 4; ++sub) {
    __syncthreads();  // prefetch for this sub-tile complete
    int cur = sub & 1;
    if (sub < 3) {
#pragma unroll
      for (int jj = 0; jj < 8; ++jj) {
        int i = wave * 8 + jj;
        int c = slane ^ (((i & 3) << 2) | rlane);
        gl_lds16(bases_bf + (size_t)(n0 + (sub + 1) * 128 + i * 4 + rlane) * NK + c * 8,
                 (char*)ldsB[cur ^ 1] + i * 1024);
      }
    }
    const char* bbuf = (const char*)ldsB[cur];
    f32x4 acc[4][4];
#pragma unroll
    for (int t = 0; t < 4; ++t)
#pragma unroll
      for (int u = 0; u < 4; ++u) acc[t][u] = (f32x4){0.f, 0.f, 0.f, 0.f};
#pragma unroll
    for (int s = 0; s < 4; ++s) {
      bf16x8 bf[4];
      int s4q = s * 4 + q;
#pragma unroll
      for (int u = 0; u < 4; ++u) {
        int rw = nb + 16 * u + r;
        bf[u] = *(const bf16x8*)(bbuf + rw * 256 + ((s4q ^ r) << 4));
      }
#pragma unroll
      for (int t = 0; t < 4; ++t)
#pragma unroll
        for (int u = 0; u < 4; ++u)
          acc[t][u] = __builtin_amdgcn_mfma_f32_16x16x32_bf16(af[t][s], bf[u],
                                                              acc[t][u], 0, 0, 0);
    }
    int rq = q * 4;
#pragma unroll
    for (int t = 0; t < 4; ++t)
#pragma unroll
      for (int u = 0; u < 4; ++u)
#pragma unroll
        for (int v = 0; v < 4; ++v)
          out[(size_t)(mo0 + mb + 16 * t + rq + v) * NSP + n0 + sub * 128 +
              nb + 16 * u + r] = acc[t][u][v];
  }
}

// ---------------------------------------------------------------------------
extern "C" void kernel_launch(void* const* d_in, const int* in_sizes, int n_in,
                              void* d_out, int out_size, void* d_ws, size_t ws_size,
                              hipStream_t stream) {
  const float* x = (const float*)d_in[0];       // (16,128,16384)
  const float* wbases = (const float*)d_in[1];  // (16384,128)
  const float* bases = (const float*)d_in[2];   // (16384,128)
  const float* W = (const float*)d_in[3];       // (128,128,128)
  float* out = (float*)d_out;                   // (16,128,16384)

  char* ws = (char*)d_ws;
  // ws layout (MB): wbT 0..4 | bases_bf 4..8 | part 8..40 | x_co 40..41 | xhat 41..41.5
  if (ws_size < ((size_t)42 << 20)) return;
  unsigned short* wbT = (unsigned short*)(ws);
  unsigned short* bases_bf = (unsigned short*)(ws + ((size_t)4 << 20));
  float* part = (float*)(ws + ((size_t)8 << 20));
  float* x_co = (float*)(ws + ((size_t)40 << 20));
  unsigned short* xhat_bf = (unsigned short*)(ws + ((size_t)41 << 20));

  k0_prep<<<4096, 256, 0, stream>>>(wbases, wbT, bases, bases_bf);
  k1_proj<<<NB * SPLIT, 512, 0, stream>>>(x, wbT, part);
  k1b_reduce<<<512, 256, 0, stream>>>(part, x_co);
  k2_mix<<<NB * NC / 2, 128, 0, stream>>>(x_co, W, xhat_bf);
  k3_recon<<<512, 256, 0, stream>>>(xhat_bf, bases_bf, out);
}